// Round 7
// baseline (52.028 us; speedup 1.0000x reference)
//
#include <hip/hip_runtime.h>

#define NPROLIF 12
#define NLIN 18
#define ROW 22                      // floats per element row
#define BLK 256
#define NSLAB 8192                  // B*T/BLK

#define AS1 __attribute__((address_space(1)))
#define AS3 __attribute__((address_space(3)))

// branchless 4-way select (lane-uniform index): v_cndmask chain on VALU
__device__ __forceinline__ float sel4(unsigned i, float x0, float x1, float x2, float x3) {
    float lo = (i & 1u) ? x1 : x0;
    float hi = (i & 1u) ? x3 : x2;
    return (i & 2u) ? hi : lo;
}

__global__ __launch_bounds__(BLK) void sindy_kernel(
    const float* __restrict__ cand,
    const float* __restrict__ a,
    const float* __restrict__ ss,
    const float* __restrict__ sgn,
    const float* __restrict__ K1p,
    const float* __restrict__ thetap,
    const float* __restrict__ K2p,
    const int* __restrict__ pidx,
    const int* __restrict__ lidx,
    const int* __restrict__ sprop,
    float* __restrict__ out)
{
    // wave-private everything: no __syncthreads in this kernel
    __shared__ float sRow[BLK*ROW];      // 22528 B, 4 x 5632 B wave slices
    __shared__ uint2 sPP[4][NPROLIF];    // per-wave tables
    __shared__ uint4 sLP[4][NLIN];
    __shared__ float sScal[4][4];        // K1, invTheta, K2, coef0

    const int tid  = threadIdx.x;
    const int lane = tid & 63;
    const int wv   = tid >> 6;

    // ---- wave-private DMA staging: 7 issues (5x16B + 2x4B), linear dest ----
    const float* gw = cand + (size_t)blockIdx.x * (BLK*ROW) + wv * (64*ROW);
    float* lw = &sRow[wv * (64*ROW)];
    #pragma unroll
    for (int k = 0; k < 5; ++k)
        __builtin_amdgcn_global_load_lds((const AS1 void*)(gw + k*256 + lane*4),
                                         (AS3 void*)(lw + k*256), 16, 0, 0);
    #pragma unroll
    for (int j = 0; j < 2; ++j)
        __builtin_amdgcn_global_load_lds((const AS1 void*)(gw + 1280 + j*64 + lane),
                                         (AS3 void*)(lw + 1280 + j*64), 4, 0, 0);

    // ---- per-wave table build, per-lane VECTOR loads (no scalar-load chains);
    //      overlaps the DMA latency. keep = sprop XOR signbit(a); a==+0 edge
    //      gives coef 0 either way.
    if (lane < NPROLIF) {
        int t = lane;
        int ia = pidx[t*3+0], ib = pidx[t*3+1], ic = pidx[t*3+2];
        unsigned avb = __float_as_uint(a[1+t]);
        unsigned keep = ((sprop[1+t] != 0) ? 1u : 0u) ^ (avb >> 31);
        unsigned offs = (unsigned)ia | ((unsigned)ib << 2) | ((unsigned)(16 + ic*4) << 8);
        sPP[wv][t] = make_uint2(offs, keep ? avb : 0u);
    } else if (lane < NPROLIF + NLIN) {          // lanes 12..29
        int j = lane - NPROLIF;
        int i0 = lidx[j*2+0], i1 = lidx[j*2+1];
        unsigned avb = __float_as_uint(a[1+NPROLIF+j]);
        unsigned keep = ((sprop[1+NPROLIF+j] != 0) ? 1u : 0u) ^ (avb >> 31);
        unsigned offs = (unsigned)i0 | ((unsigned)(16 + i1*4) << 8);
        unsigned A = 0x43fa0000u | (__float_as_uint(sgn[j]) & 0x80000000u);  // 500*sign
        sLP[wv][j] = make_uint4(offs, keep ? avb : 0u, A, __float_as_uint(ss[i1]));
    } else if (lane == NPROLIF + NLIN) {         // lane 30
        unsigned avb = __float_as_uint(a[0]);
        unsigned keep = ((sprop[0] != 0) ? 1u : 0u) ^ (avb >> 31);
        sScal[wv][0] = K1p[0];
        sScal[wv][1] = __builtin_amdgcn_rcpf(thetap[0]);   // theta=2 -> exact
        sScal[wv][2] = K2p[0];
        sScal[wv][3] = __uint_as_float(keep ? avb : 0u);
    }

    // wait ONLY this wave's DMA + table loads + ds_writes; no barrier
    asm volatile("s_waitcnt vmcnt(0) lgkmcnt(0)" ::: "memory");
    __builtin_amdgcn_sched_barrier(0);

    const char* row = (const char*)&sRow[tid*ROW];   // [con, x0,x1,x2, prot0..17]
    float con = sRow[tid*ROW+0];
    float x0  = sRow[tid*ROW+1];
    float x1  = sRow[tid*ROW+2];
    float x2  = sRow[tid*ROW+3];
    float xs  = x0 + x1 + x2;

    const float K1    = sScal[wv][0];
    const float invTh = sScal[wv][1];
    const float K2    = sScal[wv][2];
    float acc = sScal[wv][3] * con;                  // con term

    #pragma unroll
    for (int t = 0; t < NPROLIF; ++t) {
        uint2 pp = sPP[wv][t];
        float coef = __uint_as_float(pp.y);
        float pA = sel4(pp.x & 3u, x0, x1, x2, xs);
        float pB = sel4((pp.x >> 2) & 3u, x0, x1, x2, xs);
        float pC = *(const float*)(row + ((pp.x >> 8) & 0xffu));   // LDS gather
        float h  = pC * __builtin_amdgcn_rcpf(K1 + pC);
        acc += coef * (pA * (1.0f - pB * invTh) * h);
    }

    #pragma unroll
    for (int t = 0; t < NLIN; ++t) {
        uint4 lp = sLP[wv][t];
        float coef = __uint_as_float(lp.y);
        float A    = __uint_as_float(lp.z);          // 500*sign
        float ssv  = __uint_as_float(lp.w);
        float l0 = sel4(lp.x & 3u, x0, x1, x2, xs);
        float pr = *(const float*)(row + ((lp.x >> 8) & 0xffu));   // LDS gather
        float dp  = pr - ssv;
        float adp = fabsf(dp);
        float h   = adp * __builtin_amdgcn_rcpf(K2 + adp);
        float e   = __expf(-(A * dp - 25.0f));       // 500*(sign*dp - 0.05)
        float sig = __builtin_amdgcn_rcpf(1.0f + e);
        acc += coef * (l0 * h * sig);
    }

    out[(size_t)blockIdx.x * BLK + tid] = acc;
}

extern "C" void kernel_launch(void* const* d_in, const int* in_sizes, int n_in,
                              void* d_out, int out_size, void* d_ws, size_t ws_size,
                              hipStream_t stream) {
    const float* cand = (const float*)d_in[0];
    const float* a    = (const float*)d_in[1];
    const float* ss   = (const float*)d_in[2];
    const float* sgn  = (const float*)d_in[3];
    const float* K1   = (const float*)d_in[4];
    const float* th   = (const float*)d_in[5];
    const float* K2   = (const float*)d_in[6];
    const int*   pidx = (const int*)d_in[7];
    const int*   lidx = (const int*)d_in[8];
    const int*   sp   = (const int*)d_in[9];
    float* out = (float*)d_out;

    hipLaunchKernelGGL(sindy_kernel, dim3(NSLAB), dim3(BLK), 0, stream,
                       cand, a, ss, sgn, K1, th, K2, pidx, lidx, sp, out);
}

// Round 8
// 46.178 us; speedup vs baseline: 1.1267x; 1.1267x over previous
//
#include <hip/hip_runtime.h>

#define NPROLIF 12
#define NLIN 18
#define ROW 22                      // floats per element row
#define BLK 256
#define NSLAB 8192                  // B*T/BLK
#define GRID 1536                   // 6 blocks/CU (LDS: 6 x ~23KB = 138KB < 160KB)
#define F4_PER_SLAB (BLK*ROW/4)     // 1408 float4 per slab

// branchless 4-way select (wave-uniform index): v_cndmask chain
__device__ __forceinline__ float sel4(unsigned i, float x0, float x1, float x2, float x3) {
    float lo = (i & 1u) ? x1 : x0;
    float hi = (i & 1u) ? x3 : x2;
    return (i & 2u) ? hi : lo;
}

__global__ __launch_bounds__(BLK) void sindy_kernel(
    const float* __restrict__ cand,
    const float* __restrict__ a,
    const float* __restrict__ ss,
    const float* __restrict__ sgn,
    const float* __restrict__ K1p,
    const float* __restrict__ thetap,
    const float* __restrict__ K2p,
    const int* __restrict__ pidx,
    const int* __restrict__ lidx,
    const int* __restrict__ sprop,
    float* __restrict__ out)
{
    __shared__ float sRow[BLK*ROW];   // 22528 B single buffer (reg-staged double buffer)
    __shared__ uint2 sPP[NPROLIF];
    __shared__ uint4 sLP[NLIN];
    __shared__ float sScal[4];        // K1, invTheta, K2, coef0

    const int tid = threadIdx.x;
    const int bid = blockIdx.x;

    // niter: 8192 = 5*1536 + 512 -> blocks <512: 6 iters, else 5 (block-uniform)
    const int niter = (NSLAB - bid + GRID - 1) / GRID;

    // ---- per-block table build (per-lane vector loads, R6-proven) ----
    if (tid < NPROLIF) {
        int t = tid;
        int ia = pidx[t*3+0], ib = pidx[t*3+1], ic = pidx[t*3+2];
        unsigned avb  = __float_as_uint(a[1+t]);
        unsigned keep = ((sprop[1+t] != 0) ? 1u : 0u) ^ (avb >> 31);
        unsigned offs = (unsigned)ia | ((unsigned)ib << 2) | ((unsigned)(16 + ic*4) << 8);
        sPP[t] = make_uint2(offs, keep ? avb : 0u);
    } else if (tid < NPROLIF + NLIN) {           // tids 12..29
        int j = tid - NPROLIF;
        int i0 = lidx[j*2+0], i1 = lidx[j*2+1];
        unsigned avb  = __float_as_uint(a[1+NPROLIF+j]);
        unsigned keep = ((sprop[1+NPROLIF+j] != 0) ? 1u : 0u) ^ (avb >> 31);
        unsigned offs = (unsigned)i0 | ((unsigned)(16 + i1*4) << 8);
        unsigned A = 0x43fa0000u | (__float_as_uint(sgn[j]) & 0x80000000u);  // 500*sign
        sLP[j] = make_uint4(offs, keep ? avb : 0u, A, __float_as_uint(ss[i1]));
    } else if (tid == NPROLIF + NLIN) {          // tid 30
        unsigned avb  = __float_as_uint(a[0]);
        unsigned keep = ((sprop[0] != 0) ? 1u : 0u) ^ (avb >> 31);
        sScal[0] = K1p[0];
        sScal[1] = __builtin_amdgcn_rcpf(thetap[0]);   // theta=2 -> exact
        sScal[2] = K2p[0];
        sScal[3] = __uint_as_float(keep ? avb : 0u);
    }

    const float4* g4base = reinterpret_cast<const float4*>(cand);
    float4* s4 = reinterpret_cast<float4*>(sRow);
    const bool tail = (tid < F4_PER_SLAB - 5*BLK);   // last 128 float4s

    // ---- prologue: load slab0 into regs, write to LDS ----
    float4 r0, r1, r2, r3, r4, r5;
    {
        const float4* g4 = g4base + (long long)bid * F4_PER_SLAB;
        r0 = g4[tid + 0*BLK]; r1 = g4[tid + 1*BLK]; r2 = g4[tid + 2*BLK];
        r3 = g4[tid + 3*BLK]; r4 = g4[tid + 4*BLK];
        if (tail) r5 = g4[tid + 5*BLK];
    }
    s4[tid + 0*BLK] = r0; s4[tid + 1*BLK] = r1; s4[tid + 2*BLK] = r2;
    s4[tid + 3*BLK] = r3; s4[tid + 4*BLK] = r4;
    if (tail) s4[tid + 5*BLK] = r5;
    __syncthreads();                 // tables + slab0 visible

    const float K1 = sScal[0], invTh = sScal[1], K2 = sScal[2], coef0 = sScal[3];

    for (int i = 0; i < niter; ++i) {
        // ---- issue-early: prefetch slab i+1 into regs (latency hides under compute) ----
        if (i + 1 < niter) {
            const float4* g4 = g4base + (long long)(bid + (i+1)*GRID) * F4_PER_SLAB;
            r0 = g4[tid + 0*BLK]; r1 = g4[tid + 1*BLK]; r2 = g4[tid + 2*BLK];
            r3 = g4[tid + 3*BLK]; r4 = g4[tid + 4*BLK];
            if (tail) r5 = g4[tid + 5*BLK];
        }
        __builtin_amdgcn_sched_barrier(0);   // keep prefetch issues above the compute

        // ---- compute current slab from LDS ----
        const char* row = (const char*)&sRow[tid*ROW];   // [con, x0,x1,x2, prot0..17]
        float con = sRow[tid*ROW+0];
        float x0  = sRow[tid*ROW+1];
        float x1  = sRow[tid*ROW+2];
        float x2  = sRow[tid*ROW+3];
        float xs  = x0 + x1 + x2;

        float acc = coef0 * con;

        #pragma unroll
        for (int t = 0; t < NPROLIF; ++t) {
            uint2 pp = sPP[t];
            float coef = __uint_as_float(pp.y);
            float pA = sel4(pp.x & 3u, x0, x1, x2, xs);
            float pB = sel4((pp.x >> 2) & 3u, x0, x1, x2, xs);
            float pC = *(const float*)(row + ((pp.x >> 8) & 0xffu));
            float h  = pC * __builtin_amdgcn_rcpf(K1 + pC);
            acc += coef * (pA * (1.0f - pB * invTh) * h);
        }

        #pragma unroll
        for (int t = 0; t < NLIN; ++t) {
            uint4 lp = sLP[t];
            float coef = __uint_as_float(lp.y);
            float A    = __uint_as_float(lp.z);          // 500*sign
            float ssv  = __uint_as_float(lp.w);
            float l0 = sel4(lp.x & 3u, x0, x1, x2, xs);
            float pr = *(const float*)(row + ((lp.x >> 8) & 0xffu));
            float dp  = pr - ssv;
            float adp = fabsf(dp);
            float h   = adp * __builtin_amdgcn_rcpf(K2 + adp);
            float e   = __expf(-(A * dp - 25.0f));       // 500*(sign*dp - 0.05)
            float sig = __builtin_amdgcn_rcpf(1.0f + e);
            acc += coef * (l0 * h * sig);
        }

        out[(long long)(bid + i*GRID) * BLK + tid] = acc;

        // ---- write-late: retire prefetch into LDS for the next iteration ----
        if (i + 1 < niter) {
            __syncthreads();                 // all waves done reading sRow
            s4[tid + 0*BLK] = r0; s4[tid + 1*BLK] = r1; s4[tid + 2*BLK] = r2;
            s4[tid + 3*BLK] = r3; s4[tid + 4*BLK] = r4;
            if (tail) s4[tid + 5*BLK] = r5;
            __syncthreads();                 // next slab visible to all waves
        }
    }
}

extern "C" void kernel_launch(void* const* d_in, const int* in_sizes, int n_in,
                              void* d_out, int out_size, void* d_ws, size_t ws_size,
                              hipStream_t stream) {
    const float* cand = (const float*)d_in[0];
    const float* a    = (const float*)d_in[1];
    const float* ss   = (const float*)d_in[2];
    const float* sgn  = (const float*)d_in[3];
    const float* K1   = (const float*)d_in[4];
    const float* th   = (const float*)d_in[5];
    const float* K2   = (const float*)d_in[6];
    const int*   pidx = (const int*)d_in[7];
    const int*   lidx = (const int*)d_in[8];
    const int*   sp   = (const int*)d_in[9];
    float* out = (float*)d_out;

    hipLaunchKernelGGL(sindy_kernel, dim3(GRID), dim3(BLK), 0, stream,
                       cand, a, ss, sgn, K1, th, K2, pidx, lidx, sp, out);
}